// Round 1
// baseline (410.057 us; speedup 1.0000x reference)
//
#include <hip/hip_runtime.h>
#include <math.h>

// Problem constants (B,C,H,W) = (16,20,256,256), fp32 in, 4 fp32 scalars out.
constexpr int Bn = 16, Cn = 20, Hn = 256, Wn = 256;
constexpr int BCn = Bn * Cn;                 // 320 slices
constexpr int HWn = Hn * Wn;                 // 65536 per slice
constexpr int SPLIT = 4;                     // blocks per slice (4 -> whole grid co-resident)
constexpr int NBLK = BCn * SPLIT;            // 1280 blocks = 5 blocks/CU, zero tail
constexpr int CHUNK = HWn / SPLIT;           // 16384 elems per block
constexpr int TPB = 256;
constexpr int V4 = CHUNK / (TPB * 4);        // 16 float4 per thread
constexpr int NSLOT = 10;
// ws layout is TRANSPOSED: ws[slot * NBLK + blk]
// slots: 0 mass, 1 sum(t*y), 2 sum(t*x), 3 sum(p), 4 sum(p*y), 5 sum(p*x),
//        6 sum(p*(y^2+x^2)), 7 SUM(at*om^2*log2(pt))  [x ln2, negated in finalize],
//        8 (pred-t)^2, 9 |pred|

__device__ inline float wave_reduce(float v) {
    #pragma unroll
    for (int o = 32; o > 0; o >>= 1) v += __shfl_down(v, o, 64);
    return v;
}

// __launch_bounds__(256, 8): request 8 waves/EU -> compiler caps VGPRs at 64.
// Previous version sat at 68 VGPRs, just over the 64-reg occupancy cliff
// (8 -> 4 waves/SIMD), which is why OccupancyPercent was 22%.
__global__ __launch_bounds__(TPB, 8) void partials_kernel(
        const float* __restrict__ pred, const float* __restrict__ target,
        float* __restrict__ ws) {
    const int blk = blockIdx.x;
    const int bc = blk >> 2;                 // / SPLIT
    const int chunk = blk & (SPLIT - 1);
    const long long base = (long long)bc * HWn + (long long)chunk * CHUNK;
    const float4* __restrict__ p4 = (const float4*)(pred + base);
    const float4* __restrict__ t4 = (const float4*)(target + base);
    const int tid = threadIdx.x;

    float acc[NSLOT];
    #pragma unroll
    for (int k = 0; k < NSLOT; k++) acc[k] = 0.f;

    // Element index in slice = chunk*CHUNK + tid*4 + i*1024.
    // i*1024 is a multiple of W=256 -> x (column) is loop-invariant,
    // y advances by exactly 4 rows per iteration; all 4 lanes of a float4
    // share the same y, so y-moments are accumulated once per iteration
    // from row partial sums (st4 / sp4).
    const int e_base = chunk * CHUNK + tid * 4;
    const float x0 = (float)(e_base & 255);
    const float xs[4]  = {x0, x0 + 1.f, x0 + 2.f, x0 + 3.f};
    const float xxs[4] = {xs[0] * xs[0], xs[1] * xs[1], xs[2] * xs[2], xs[3] * xs[3]};
    float y = (float)(e_base >> 8);

    constexpr float L2E = 1.44269504088896f;   // log2(e)

    float4 pc = p4[tid];
    float4 tc = t4[tid];

    #pragma unroll
    for (int i = 0; i < V4; i++) {
        float4 pn, tn;
        if (i + 1 < V4) {                    // depth-1 rotating prefetch
            pn = p4[(i + 1) * TPB + tid];
            tn = t4[(i + 1) * TPB + tid];
        }
        const float yy = y * y;
        const float pv[4] = {pc.x, pc.y, pc.z, pc.w};
        const float tv[4] = {tc.x, tc.y, tc.z, tc.w};
        float st4 = 0.f, sp4 = 0.f;
        #pragma unroll
        for (int j = 0; j < 4; j++) {
            const float v = pv[j];
            const float t = tv[j];           // exactly 0.0 or 1.0
            // sigmoid + focal in log2 domain: u = v*log2(e), e^{-v} = exp2(-u),
            // log2(pt) = log2(p) - (1-t)*u. The final ln2 scale is applied once
            // in finalize (focal sum is linear). Branchless via t in {0,1}:
            const float u  = v * L2E;
            const float e  = __builtin_amdgcn_exp2f(-u);
            const float p  = __builtin_amdgcn_rcpf(1.0f + e);   // sigmoid
            const float l2p = __builtin_amdgcn_logf(p);         // log2(p)
            const float l2pt = fmaf(t, u, l2p - u);             // log2(pt)
            const float w1 = fmaf(p, -2.0f, 1.0f);              // 1 - 2p
            const float om = fmaf(t, w1, p);                    // 1 - pt
            const float at = fmaf(t, -0.5f, 0.75f);             // alpha_t
            acc[7] = fmaf(at * l2pt, om * om, acc[7]);          // * ln2, negate later
            // sparsity
            const float d = v - t;
            acc[8] = fmaf(d, d, acc[8]);
            acc[9] += fabsf(v);
            // concentration partials (x-moments per element, y-moments per row)
            st4 += t;
            acc[2] = fmaf(t, xs[j], acc[2]);
            sp4 += p;
            acc[5] = fmaf(p, xs[j], acc[5]);
            acc[6] = fmaf(p, xxs[j], acc[6]);
        }
        acc[0] += st4;
        acc[1] = fmaf(st4, y, acc[1]);
        acc[3] += sp4;
        acc[4] = fmaf(sp4, y, acc[4]);
        acc[6] = fmaf(sp4, yy, acc[6]);
        y += 4.0f;
        if (i + 1 < V4) { pc = pn; tc = tn; }
    }

    __shared__ float lds[TPB / 64][NSLOT];
    const int lane = tid & 63, wave = tid >> 6;
    #pragma unroll
    for (int k = 0; k < NSLOT; k++) {
        const float r = wave_reduce(acc[k]);
        if (lane == 0) lds[wave][k] = r;
    }
    __syncthreads();
    if (tid < NSLOT) {
        float s = 0.f;
        #pragma unroll
        for (int w = 0; w < TPB / 64; w++) s += lds[w][tid];
        ws[tid * NBLK + blk] = s;            // transposed store
    }
}

// 320 threads: thread tid owns slice (b,c)=tid. With SPLIT=4 and transposed ws,
// each slot's 4 partials for a slice are exactly one float4 -> 10 vector loads
// per thread, fully coalesced.
__global__ __launch_bounds__(320) void finalize_kernel(
        const float* __restrict__ ws, float* __restrict__ out) {
    const int tid = threadIdx.x;
    const float4* __restrict__ w4 = (const float4*)ws;
    // slot k row in float4 units: k * (NBLK/4) = k * 320

    float s[NSLOT];
    #pragma unroll
    for (int k = 0; k < NSLOT; k++) {
        const float4 v = w4[k * (NBLK / 4) + tid];
        s[k] = v.x + v.y + v.z + v.w;
    }

    // ---- per-(b,c) concentration term ----
    const float mass = s[0];
    const bool valid = mass > 0.f;
    const float sm = valid ? mass : 1.0f;
    const float cy = s[1] / sm, cx = s[2] / sm;
    const float pdsq = s[6] - 2.f * cy * s[4] - 2.f * cx * s[5]
                     + (cy * cy + cx * cx) * s[3];
    float vals[5];
    vals[0] = valid ? (pdsq / (float)HWn) : 0.f;   // conc per-sample mean
    vals[1] = valid ? 1.f : 0.f;                   // n_valid
    vals[2] = s[7];                                // focal sum (log2 domain)
    vals[3] = s[8];                                // sum (pred-t)^2
    vals[4] = s[9];                                // sum |pred|

    __shared__ float lds[5][5];
    const int lane = tid & 63, wave = tid >> 6;
    #pragma unroll
    for (int k = 0; k < 5; k++) {
        const float r = wave_reduce(vals[k]);
        if (lane == 0) lds[wave][k] = r;
    }
    __syncthreads();

    if (tid == 0) {
        float tot[5];
        #pragma unroll
        for (int k = 0; k < 5; k++) {
            float acc = 0.f;
            #pragma unroll
            for (int w = 0; w < 5; w++) acc += lds[w][k];
            tot[k] = acc;
        }
        const float NTOT = (float)Bn * Cn * Hn * Wn;   // 20971520
        constexpr float LN2 = 0.69314718055994531f;
        const float focal = -LN2 * tot[2] / NTOT;      // restore ln from log2
        const float sparsity = tot[3] / NTOT + tot[4] / NTOT;
        const float concentration =
            (tot[1] > 0.f) ? (tot[0] / fmaxf(tot[1], 1.f)) : 0.f;
        const float total = 1.0f * focal + 0.8f * sparsity + 1.5f * concentration;
        out[0] = total;
        out[1] = focal;
        out[2] = sparsity;
        out[3] = concentration;
    }
}

extern "C" void kernel_launch(void* const* d_in, const int* in_sizes, int n_in,
                              void* d_out, int out_size, void* d_ws, size_t ws_size,
                              hipStream_t stream) {
    const float* pred   = (const float*)d_in[0];
    const float* target = (const float*)d_in[1];
    float* out = (float*)d_out;
    float* ws  = (float*)d_ws;   // needs NBLK*NSLOT*4 = 51.2 KB

    partials_kernel<<<NBLK, TPB, 0, stream>>>(pred, target, ws);
    finalize_kernel<<<1, 320, 0, stream>>>(ws, out);
}

// Round 2
// 186.259 us; speedup vs baseline: 2.2015x; 2.2015x over previous
//
#include <hip/hip_runtime.h>
#include <math.h>

// Problem constants (B,C,H,W) = (16,20,256,256), fp32 in, 4 fp32 scalars out.
constexpr int Bn = 16, Cn = 20, Hn = 256, Wn = 256;
constexpr int BCn = Bn * Cn;                 // 320 slices
constexpr int HWn = Hn * Wn;                 // 65536 per slice
constexpr int SPLIT = 16;                    // blocks per slice
constexpr int NBLK = BCn * SPLIT;            // 5120 blocks = 5 * (1024 resident) -> zero tail
constexpr int CHUNK = HWn / SPLIT;           // 4096 elems per block
constexpr int TPB = 256;
constexpr int V4 = CHUNK / (TPB * 4);        // 4 float4 per thread -> preload ALL
constexpr int NSLOT = 10;
// ws layout is TRANSPOSED: ws[slot * NBLK + blk]   (needs NBLK*NSLOT*4 = 204.8 KB)
// slots: 0 mass, 1 sum(t*y), 2 sum(t*x), 3 sum(p), 4 sum(p*y), 5 sum(p*x),
//        6 sum(p*(y^2+x^2)), 7 SUM(at*om^2*log2(pt))  [x ln2, negated in finalize],
//        8 (pred-t)^2, 9 |pred|

__device__ inline float wave_reduce(float v) {
    #pragma unroll
    for (int o = 32; o > 0; o >>= 1) v += __shfl_down(v, o, 64);
    return v;
}

// __launch_bounds__(TPB, 4): 128-VGPR cap. Round-1's (TPB,8) forced 32 VGPRs
// -> 380 MB scratch spill, 295 us. Live state is ~75 regs; 4 waves/SIMD is the
// honest occupancy, and we cover latency with 8 loads in flight per wave
// (all V4=4 iterations preloaded, counted vmcnt drain) instead of more waves.
__global__ __launch_bounds__(TPB, 4) void partials_kernel(
        const float* __restrict__ pred, const float* __restrict__ target,
        float* __restrict__ ws) {
    const int blk = blockIdx.x;
    const int bc = blk >> 4;                 // / SPLIT
    const int chunk = blk & (SPLIT - 1);
    const long long base = (long long)bc * HWn + (long long)chunk * CHUNK;
    const float4* __restrict__ p4 = (const float4*)(pred + base);
    const float4* __restrict__ t4 = (const float4*)(target + base);
    const int tid = threadIdx.x;

    // Issue ALL global loads up front: 8 dwordx4 in flight per wave.
    const float4 p0 = p4[0 * TPB + tid];
    const float4 t0 = t4[0 * TPB + tid];
    const float4 p1 = p4[1 * TPB + tid];
    const float4 t1 = t4[1 * TPB + tid];
    const float4 p2 = p4[2 * TPB + tid];
    const float4 t2 = t4[2 * TPB + tid];
    const float4 p3 = p4[3 * TPB + tid];
    const float4 t3 = t4[3 * TPB + tid];

    float acc[NSLOT];
    #pragma unroll
    for (int k = 0; k < NSLOT; k++) acc[k] = 0.f;

    // Element index in slice = chunk*CHUNK + tid*4 + i*1024.
    // i*1024 is a multiple of W=256 -> x (column) is loop-invariant,
    // y advances by exactly 4 rows per iteration; all 4 lanes of a float4
    // share the same y, so y-moments come from row partial sums (st4/sp4).
    const int e_base = chunk * CHUNK + tid * 4;
    const float x0 = (float)(e_base & 255);
    const float xs[4]  = {x0, x0 + 1.f, x0 + 2.f, x0 + 3.f};
    const float xxs[4] = {xs[0] * xs[0], xs[1] * xs[1], xs[2] * xs[2], xs[3] * xs[3]};
    float y = (float)(e_base >> 8);

    constexpr float L2E = 1.44269504088896f;   // log2(e)

    auto PROC = [&](const float4& pcv, const float4& tcv) {
        const float yy = y * y;
        const float pv[4] = {pcv.x, pcv.y, pcv.z, pcv.w};
        const float tv[4] = {tcv.x, tcv.y, tcv.z, tcv.w};
        float st4 = 0.f, sp4 = 0.f;
        #pragma unroll
        for (int j = 0; j < 4; j++) {
            const float v = pv[j];
            const float t = tv[j];           // exactly 0.0 or 1.0
            // sigmoid + focal in log2 domain: u = v*log2(e), e^{-v} = exp2(-u),
            // log2(pt) = log2(p) - (1-t)*u. ln2 scale applied once in finalize.
            const float u  = v * L2E;
            const float e  = __builtin_amdgcn_exp2f(-u);
            const float p  = __builtin_amdgcn_rcpf(1.0f + e);   // sigmoid
            const float l2p = __builtin_amdgcn_logf(p);         // log2(p)
            const float l2pt = fmaf(t, u, l2p - u);             // log2(pt)
            const float w1 = fmaf(p, -2.0f, 1.0f);              // 1 - 2p
            const float om = fmaf(t, w1, p);                    // 1 - pt
            const float at = fmaf(t, -0.5f, 0.75f);             // alpha_t
            acc[7] = fmaf(at * l2pt, om * om, acc[7]);          // * ln2, negate later
            // sparsity
            const float d = v - t;
            acc[8] = fmaf(d, d, acc[8]);
            acc[9] += fabsf(v);
            // concentration partials (x-moments per element, y-moments per row)
            st4 += t;
            acc[2] = fmaf(t, xs[j], acc[2]);
            sp4 += p;
            acc[5] = fmaf(p, xs[j], acc[5]);
            acc[6] = fmaf(p, xxs[j], acc[6]);
        }
        acc[0] += st4;
        acc[1] = fmaf(st4, y, acc[1]);
        acc[3] += sp4;
        acc[4] = fmaf(sp4, y, acc[4]);
        acc[6] = fmaf(sp4, yy, acc[6]);
        y += 4.0f;
    };

    PROC(p0, t0);
    PROC(p1, t1);
    PROC(p2, t2);
    PROC(p3, t3);

    __shared__ float lds[TPB / 64][NSLOT];
    const int lane = tid & 63, wave = tid >> 6;
    #pragma unroll
    for (int k = 0; k < NSLOT; k++) {
        const float r = wave_reduce(acc[k]);
        if (lane == 0) lds[wave][k] = r;
    }
    __syncthreads();
    if (tid < NSLOT) {
        float s = 0.f;
        #pragma unroll
        for (int w = 0; w < TPB / 64; w++) s += lds[w][tid];
        ws[tid * NBLK + blk] = s;            // transposed store
    }
}

// 320 threads: thread tid owns slice (b,c)=tid. With transposed ws, slice tid's
// SPLIT=16 partials for slot k are float4s [k*1280 + 4*tid .. +3].
__global__ __launch_bounds__(320) void finalize_kernel(
        const float* __restrict__ ws, float* __restrict__ out) {
    const int tid = threadIdx.x;
    const float4* __restrict__ w4 = (const float4*)ws;

    float s[NSLOT];
    #pragma unroll
    for (int k = 0; k < NSLOT; k++) {
        float a = 0.f;
        #pragma unroll
        for (int q = 0; q < SPLIT / 4; q++) {
            const float4 v = w4[k * (NBLK / 4) + tid * (SPLIT / 4) + q];
            a += v.x + v.y + v.z + v.w;
        }
        s[k] = a;
    }

    // ---- per-(b,c) concentration term ----
    const float mass = s[0];
    const bool valid = mass > 0.f;
    const float sm = valid ? mass : 1.0f;
    const float cy = s[1] / sm, cx = s[2] / sm;
    const float pdsq = s[6] - 2.f * cy * s[4] - 2.f * cx * s[5]
                     + (cy * cy + cx * cx) * s[3];
    float vals[5];
    vals[0] = valid ? (pdsq / (float)HWn) : 0.f;   // conc per-sample mean
    vals[1] = valid ? 1.f : 0.f;                   // n_valid
    vals[2] = s[7];                                // focal sum (log2 domain)
    vals[3] = s[8];                                // sum (pred-t)^2
    vals[4] = s[9];                                // sum |pred|

    __shared__ float lds[5][5];
    const int lane = tid & 63, wave = tid >> 6;
    #pragma unroll
    for (int k = 0; k < 5; k++) {
        const float r = wave_reduce(vals[k]);
        if (lane == 0) lds[wave][k] = r;
    }
    __syncthreads();

    if (tid == 0) {
        float tot[5];
        #pragma unroll
        for (int k = 0; k < 5; k++) {
            float a = 0.f;
            #pragma unroll
            for (int w = 0; w < 5; w++) a += lds[w][k];
            tot[k] = a;
        }
        const float NTOT = (float)Bn * Cn * Hn * Wn;   // 20971520
        constexpr float LN2 = 0.69314718055994531f;
        const float focal = -LN2 * tot[2] / NTOT;      // restore ln from log2
        const float sparsity = tot[3] / NTOT + tot[4] / NTOT;
        const float concentration =
            (tot[1] > 0.f) ? (tot[0] / fmaxf(tot[1], 1.f)) : 0.f;
        const float total = 1.0f * focal + 0.8f * sparsity + 1.5f * concentration;
        out[0] = total;
        out[1] = focal;
        out[2] = sparsity;
        out[3] = concentration;
    }
}

extern "C" void kernel_launch(void* const* d_in, const int* in_sizes, int n_in,
                              void* d_out, int out_size, void* d_ws, size_t ws_size,
                              hipStream_t stream) {
    const float* pred   = (const float*)d_in[0];
    const float* target = (const float*)d_in[1];
    float* out = (float*)d_out;
    float* ws  = (float*)d_ws;   // needs NBLK*NSLOT*4 = 204.8 KB

    partials_kernel<<<NBLK, TPB, 0, stream>>>(pred, target, ws);
    finalize_kernel<<<1, 320, 0, stream>>>(ws, out);
}